// Round 5
// baseline (279.112 us; speedup 1.0000x reference)
//
#include <hip/hip_runtime.h>
#include <hip/hip_bf16.h>
#include <stdint.h>

#define SLOPE 0.2f

typedef short s16x8 __attribute__((ext_vector_type(8)));
typedef float f32x4 __attribute__((ext_vector_type(4)));

__device__ __forceinline__ unsigned short f2bf(float x) {
    union { float f; uint32_t u; } v; v.f = x;
    uint32_t u = v.u;
    return (unsigned short)((u + 0x7FFFu + ((u >> 16) & 1u)) >> 16);  // RNE
}

// Roles (592 blocks):
//   0..127   transpose W_node -> W_T (bf16)        -> cntA (target 128)
//   128..255 GEMM g = h @ W_node + s_i/s_j          (spin cntA) -> cntB
//   256..319 edge scores s_e (computes wv locally)             -> cntB
//   320..335 row_start scans                                   -> cntB
//   336..591 attn (4 rows/block, wave-per-row)      (spin cntB, target 208)
// Co-residency: __launch_bounds__(256,4) => VGPR<=128 => >=4 blocks/CU => >=1024
// resident blocks > 592 total, so spin-wait cannot deadlock.
__global__ __launch_bounds__(256, 4)
void fused_kernel(const float* __restrict__ hmat,       // [1024][1024]
                  const float* __restrict__ adj,        // [16][64][64]
                  const float* __restrict__ edge_attr,  // [16384][128]
                  const float* __restrict__ W_node,     // [1024][512]
                  const float* __restrict__ W_edge,     // [128][512]
                  const float* __restrict__ w_attn,     // [192]
                  unsigned short* __restrict__ W_T,     // [512][1024] bf16
                  float* __restrict__ g,                // [1024][512]
                  float* __restrict__ s_e,              // [16384][8]
                  float* __restrict__ s_i,              // [1024][8]
                  float* __restrict__ s_j,              // [1024][8]
                  int* __restrict__ row_start,          // [1024]
                  int* __restrict__ cntA,
                  int* __restrict__ cntB,
                  float* __restrict__ out)              // [1024][512]
{
    __shared__ __align__(16) char smem[20608];   // union across roles (max: GEMM 20480)
    int bx = blockIdx.x;
    int tid = threadIdx.x;

    if (bx < 128) {
        // ================= transpose role =================
        float (*tile)[65] = (float (*)[65])smem;          // 64*65*4 = 16640 B
        int tn = bx & 7, tk = bx >> 3;
        int k0 = tk * 64, n0 = tn * 64;
        #pragma unroll
        for (int j = 0; j < 16; ++j) {
            int lin = j * 256 + tid;
            int r = lin >> 6, c = lin & 63;
            tile[r][c] = W_node[(size_t)(k0 + r) * 512 + n0 + c];
        }
        __syncthreads();
        #pragma unroll
        for (int j = 0; j < 16; ++j) {
            int lin = j * 256 + tid;
            int nr = lin >> 6, kc = lin & 63;
            W_T[(size_t)(n0 + nr) * 1024 + k0 + kc] = f2bf(tile[kc][nr]);
        }
        __threadfence();
        __syncthreads();
        if (tid == 0)
            __hip_atomic_fetch_add(cntA, 1, __ATOMIC_RELEASE, __HIP_MEMORY_SCOPE_AGENT);
    } else if (bx < 256) {
        // ================= GEMM role (round-4 body, bitwise-identical) ========
        unsigned short* As = (unsigned short*)smem;            // [2][64][40]
        unsigned short* Bs = (unsigned short*)(smem + 10240);  // [2][64][40]
        int rb = bx - 128;
        int head = rb & 7, mt = rb >> 3;
        int n0 = head * 64, m0 = mt * 64;
        int wave = tid >> 6, lane = tid & 63;
        int l15 = lane & 15, quad = lane >> 4;
        int wv16 = wave * 16;
        int ldr = tid >> 2;
        int ldc8 = (tid & 3) * 8;

        const float* apBase = hmat + (size_t)(m0 + ldr) * 1024 + ldc8;
        const unsigned short* bpBase = W_T + (size_t)(n0 + ldr) * 1024 + ldc8;

        f32x4 acc[4];
        #pragma unroll
        for (int i = 0; i < 4; ++i) acc[i] = (f32x4){0.f, 0.f, 0.f, 0.f};

        // prefetch A iter0 (independent of transpose), then wait for W_T
        float4 a0 = *(const float4*)(apBase);
        float4 a1 = *(const float4*)(apBase + 4);
        if (tid == 0) {
            int it = 0;
            while (__hip_atomic_load(cntA, __ATOMIC_ACQUIRE, __HIP_MEMORY_SCOPE_AGENT) < 128
                   && ++it < (1 << 24))
                __builtin_amdgcn_s_sleep(2);
        }
        __syncthreads();

        int4 bv = *(const int4*)(bpBase);
        {
            s16x8 av;
            av[0] = (short)f2bf(a0.x); av[1] = (short)f2bf(a0.y);
            av[2] = (short)f2bf(a0.z); av[3] = (short)f2bf(a0.w);
            av[4] = (short)f2bf(a1.x); av[5] = (short)f2bf(a1.y);
            av[6] = (short)f2bf(a1.z); av[7] = (short)f2bf(a1.w);
            *(s16x8*)&As[ldr * 40 + ldc8] = av;
            *(int4*)&Bs[ldr * 40 + ldc8] = bv;
        }

        for (int it = 0; it < 32; ++it) {
            __syncthreads();
            if (it + 1 < 32) {
                const float* ap = apBase + (it + 1) * 32;
                a0 = *(const float4*)ap;
                a1 = *(const float4*)(ap + 4);
                bv = *(const int4*)(bpBase + (it + 1) * 32);
            }
            int cur = it & 1;
            s16x8 af = *(const s16x8*)&As[(cur * 64 + wv16 + l15) * 40 + quad * 8];
            #pragma unroll
            for (int nt = 0; nt < 4; ++nt) {
                s16x8 bf = *(const s16x8*)&Bs[(cur * 64 + nt * 16 + l15) * 40 + quad * 8];
                acc[nt] = __builtin_amdgcn_mfma_f32_16x16x32_bf16(af, bf, acc[nt], 0, 0, 0);
            }
            if (it + 1 < 32) {
                int nxt = (it & 1) ^ 1;
                s16x8 av;
                av[0] = (short)f2bf(a0.x); av[1] = (short)f2bf(a0.y);
                av[2] = (short)f2bf(a0.z); av[3] = (short)f2bf(a0.w);
                av[4] = (short)f2bf(a1.x); av[5] = (short)f2bf(a1.y);
                av[6] = (short)f2bf(a1.z); av[7] = (short)f2bf(a1.w);
                *(s16x8*)&As[(nxt * 64 + ldr) * 40 + ldc8] = av;
                *(int4*)&Bs[(nxt * 64 + ldr) * 40 + ldc8] = bv;
            }
        }

        float wi[4], wj[4];
        #pragma unroll
        for (int nt = 0; nt < 4; ++nt) {
            wi[nt] = w_attn[nt * 16 + l15];
            wj[nt] = w_attn[64 + nt * 16 + l15];
        }
        float pi[4], pj[4];
        #pragma unroll
        for (int reg = 0; reg < 4; ++reg) { pi[reg] = 0.f; pj[reg] = 0.f; }
        #pragma unroll
        for (int nt = 0; nt < 4; ++nt) {
            #pragma unroll
            for (int reg = 0; reg < 4; ++reg) {
                int gm = m0 + wv16 + quad * 4 + reg;
                int gn = n0 + nt * 16 + l15;
                g[(size_t)gm * 512 + gn] = acc[nt][reg];
                pi[reg] += acc[nt][reg] * wi[nt];
                pj[reg] += acc[nt][reg] * wj[nt];
            }
        }
        #pragma unroll
        for (int mask = 1; mask < 16; mask <<= 1) {
            #pragma unroll
            for (int reg = 0; reg < 4; ++reg) {
                pi[reg] += __shfl_xor(pi[reg], mask);
                pj[reg] += __shfl_xor(pj[reg], mask);
            }
        }
        if (l15 == 0) {
            #pragma unroll
            for (int reg = 0; reg < 4; ++reg) {
                int r = m0 + wv16 + quad * 4 + reg;
                s_i[(size_t)r * 8 + head] = pi[reg];
                s_j[(size_t)r * 8 + head] = pj[reg];
            }
        }
        __threadfence();
        __syncthreads();
        if (tid == 0)
            __hip_atomic_fetch_add(cntB, 1, __ATOMIC_RELEASE, __HIP_MEMORY_SCOPE_AGENT);
    } else if (bx < 320) {
        // ================= edge-score role (local wv, same fp order) ==========
        float* wvs = (float*)smem;                 // [128][8] = 4 KB
        {
            int c = tid & 127, half = tid >> 7;
            const float* we = w_attn + 128;
            #pragma unroll
            for (int hh = 0; hh < 4; ++hh) {
                int h = half * 4 + hh;
                float s = 0.f;
                const float* row = W_edge + (size_t)c * 512 + h * 64;
                #pragma unroll 8
                for (int f = 0; f < 64; ++f) s += row[f] * we[f];
                wvs[c * 8 + h] = s;
            }
        }
        __syncthreads();
        int e = (bx - 256) * 256 + tid;
        const float4* erow = (const float4*)(edge_attr + (size_t)e * 128);
        f32x4 accl = {0.f, 0.f, 0.f, 0.f};
        f32x4 acch = {0.f, 0.f, 0.f, 0.f};
        for (int c4 = 0; c4 < 32; ++c4) {
            float4 v = erow[c4];
            #pragma unroll
            for (int u = 0; u < 4; ++u) {
                int c = c4 * 4 + u;
                f32x4 w0 = *(const f32x4*)&wvs[c * 8];
                f32x4 w1 = *(const f32x4*)&wvs[c * 8 + 4];
                float x = (u == 0) ? v.x : (u == 1) ? v.y : (u == 2) ? v.z : v.w;
                accl += x * w0;
                acch += x * w1;
            }
        }
        *(f32x4*)(s_e + (size_t)e * 8)     = accl;
        *(f32x4*)(s_e + (size_t)e * 8 + 4) = acch;
        __threadfence();
        __syncthreads();
        if (tid == 0)
            __hip_atomic_fetch_add(cntB, 1, __ATOMIC_RELEASE, __HIP_MEMORY_SCOPE_AGENT);
    } else if (bx < 336) {
        // ================= row_start role =================
        int b = bx - 320;
        if (tid < 64) {
            const float* row = adj + (size_t)b * 4096 + (size_t)tid * 64;
            int cnt = 0;
            #pragma unroll 8
            for (int j = 0; j < 64; ++j) cnt += (row[j] > 0.5f) ? 1 : 0;
            int inc = cnt;
            #pragma unroll
            for (int d = 1; d < 64; d <<= 1) {
                int u = __shfl_up(inc, d, 64);
                if (tid >= d) inc += u;
            }
            row_start[b * 64 + tid] = inc - cnt;
        }
        __threadfence();
        __syncthreads();
        if (tid == 0)
            __hip_atomic_fetch_add(cntB, 1, __ATOMIC_RELEASE, __HIP_MEMORY_SCOPE_AGENT);
    } else {
        // ================= attn role: wave-per-row, no LDS g staging ==========
        float* a_s = (float*)smem;                 // [4][16][8] = 2 KB
        int*   nbr = (int*)(smem + 2048);          // [4][16]
        int bi4 = bx - 336;                        // 0..255
        int b = bi4 >> 4;
        int i = (bi4 & 15) * 4 + (tid >> 6);       // wave w -> row i0+w
        int w = tid >> 6, lane = tid & 63;
        int bi = b * 64 + i;

        // neighbor ballot (inputs only — safe before spin)
        float av = adj[(size_t)b * 4096 + (size_t)i * 64 + lane];
        unsigned long long m = __ballot(av > 0.5f);
        int m_nb = __popcll(m); m_nb = (m_nb > 16) ? 16 : m_nb;
        int r = __popcll(m & ((1ull << lane) - 1ull));
        if ((av > 0.5f) && r < 16) nbr[w * 16 + r] = lane;

        if (tid == 0) {
            int it = 0;
            while (__hip_atomic_load(cntB, __ATOMIC_ACQUIRE, __HIP_MEMORY_SCOPE_AGENT) < 208
                   && ++it < (1 << 24))
                __builtin_amdgcn_s_sleep(2);
        }
        __syncthreads();

        int rs = row_start[bi];

        // scores: 16-lane groups, 2 heads each
        int k = lane & 15, g2 = lane >> 4;
        int h0 = g2 * 2, h1 = h0 + 1;
        float sc0 = -1e30f, sc1 = -1e30f;
        int jn = nbr[w * 16 + k];
        if (k < m_nb) {
            float v0 = s_i[(size_t)bi * 8 + h0] + s_j[(size_t)(b * 64 + jn) * 8 + h0]
                     + s_e[(size_t)(b * 1024 + rs + k) * 8 + h0];
            float v1 = s_i[(size_t)bi * 8 + h1] + s_j[(size_t)(b * 64 + jn) * 8 + h1]
                     + s_e[(size_t)(b * 1024 + rs + k) * 8 + h1];
            sc0 = (v0 >= 0.f) ? v0 : SLOPE * v0;
            sc1 = (v1 >= 0.f) ? v1 : SLOPE * v1;
        }
        float mx0 = sc0, mx1 = sc1;
        #pragma unroll
        for (int mask = 1; mask < 16; mask <<= 1) {
            mx0 = fmaxf(mx0, __shfl_xor(mx0, mask));
            mx1 = fmaxf(mx1, __shfl_xor(mx1, mask));
        }
        float e0 = (k < m_nb) ? __expf(sc0 - mx0) : 0.f;
        float e1 = (k < m_nb) ? __expf(sc1 - mx1) : 0.f;
        float t0 = e0, t1 = e1;
        #pragma unroll
        for (int mask = 1; mask < 16; mask <<= 1) {
            t0 += __shfl_xor(t0, mask);
            t1 += __shfl_xor(t1, mask);
        }
        a_s[(w * 16 + k) * 8 + h0] = e0 / t0;
        a_s[(w * 16 + k) * 8 + h1] = e1 / t1;

        // aggregation: lane owns 8 consecutive cols (one head), direct L2 reads
        int c0 = lane * 8;
        int h = lane >> 3;
        f32x4 o0 = {0.f, 0.f, 0.f, 0.f};
        f32x4 o1 = {0.f, 0.f, 0.f, 0.f};
        for (int kk = 0; kk < m_nb; ++kk) {
            float ak = a_s[(w * 16 + kk) * 8 + h];
            int jj = nbr[w * 16 + kk];
            const f32x4* gr = (const f32x4*)(g + (size_t)(b * 64 + jj) * 512 + c0);
            o0 += ak * gr[0];
            o1 += ak * gr[1];
        }
        *(f32x4*)(out + (size_t)bi * 512 + c0)     = o0;
        *(f32x4*)(out + (size_t)bi * 512 + c0 + 4) = o1;
    }
}

// ---------------------------------------------------------------------------
extern "C" void kernel_launch(void* const* d_in, const int* in_sizes, int n_in,
                              void* d_out, int out_size, void* d_ws, size_t ws_size,
                              hipStream_t stream) {
    const float* h_in      = (const float*)d_in[0];   // (16,64,1024)
    const float* adj_mat   = (const float*)d_in[1];   // (16,64,64)
    const float* edge_attr = (const float*)d_in[2];   // (16,1024,128)
    const float* W_node    = (const float*)d_in[3];   // (1024,512)
    const float* W_edge    = (const float*)d_in[4];   // (128,512)
    const float* w_attn    = (const float*)d_in[5];   // (192,)
    float* out = (float*)d_out;                       // (16,64,512) fp32

    char* ws = (char*)d_ws;
    unsigned short* W_T = (unsigned short*)(ws + 0x000000);   // 1 MB
    float* g            = (float*)(ws + 0x100000);            // 2 MB
    float* s_e          = (float*)(ws + 0x300000);            // 512 KB
    float* s_i          = (float*)(ws + 0x380000);            // 32 KB
    float* s_j          = (float*)(ws + 0x388000);            // 32 KB
    int*   row_start    = (int*)  (ws + 0x390000);            // 4 KB
    int*   flags        = (int*)  (ws + 0x3A0000);            // cntA, cntB

    hipMemsetAsync(flags, 0, 64, stream);   // graph-legal memset node
    fused_kernel<<<592, 256, 0, stream>>>(h_in, adj_mat, edge_attr,
                                          W_node, W_edge, w_attn,
                                          W_T, g, s_e, s_i, s_j, row_start,
                                          flags, flags + 1, out);
}

// Round 6
// 126.021 us; speedup vs baseline: 2.2148x; 2.2148x over previous
//
#include <hip/hip_runtime.h>
#include <hip/hip_bf16.h>
#include <stdint.h>

#define SLOPE 0.2f

typedef short s16x8 __attribute__((ext_vector_type(8)));
typedef float f32x4 __attribute__((ext_vector_type(4)));

__device__ __forceinline__ unsigned short f2bf(float x) {
    union { float f; uint32_t u; } v; v.f = x;
    uint32_t u = v.u;
    return (unsigned short)((u + 0x7FFFu + ((u >> 16) & 1u)) >> 16);  // RNE
}

// One block per (batch, head): 128 blocks, 256 threads.
// Phase G : g-tile = h[b] @ W_node[:, h*64:+64]  (bf16 MFMA, dbuf K-loop,
//           bitwise-identical MFMA stream to round 4; B transposed in-block)
// Phase E : g-tile -> LDS (fp32); fused s_i/s_j row dots (shfl reduction)
//           adj ballot -> nbr/cnt; wv[:,h]
// Phase S : row_start scan; s_e slice (16 lanes per edge, tree reduce)
// Phase X : scores + softmax (16 lanes per row)
// Phase A : out[b,:,h*64:+64] = a @ g-tile
// All dependencies intra-block: no fences, no flags, single launch.
__global__ __launch_bounds__(256)
void gat_fused(const float* __restrict__ hmat,       // [1024][1024]
               const float* __restrict__ adj,        // [16][64][64]
               const float* __restrict__ edge_attr,  // [16][1024][128]
               const float* __restrict__ W_node,     // [1024][512]
               const float* __restrict__ W_edge,     // [128][512]
               const float* __restrict__ w_attn,     // [192]
               float* __restrict__ out)              // [1024][512]
{
    __shared__ __align__(16) char U[20480];          // As/Bs during GEMM, overlay after
    __shared__ __align__(16) float gtile[64][68];    // fp32 g-tile (pad 4)

    unsigned short* As = (unsigned short*)U;             // [2][64][40]
    unsigned short* Bs = (unsigned short*)(U + 10240);   // [2][64][40]
    // post-GEMM overlay (disjoint):
    float* s_eS = (float*)U;                  // [1024]
    int*   nbrS = (int*)(U + 4096);           // [64][16]
    float* a_sS = (float*)(U + 8192);         // [64][16]
    int*   cntS = (int*)(U + 12288);          // [64]
    int*   rsS  = (int*)(U + 12544);          // [64]
    float* siS  = (float*)(U + 12800);        // [64]
    float* sjS  = (float*)(U + 13056);        // [64]
    float* wvS  = (float*)(U + 13312);        // [128]

    int bx = blockIdx.x, tid = threadIdx.x;
    int b = bx >> 3, h = bx & 7;
    int n0 = h * 64, m0 = b * 64;
    int wave = tid >> 6, lane = tid & 63;
    int l15 = lane & 15, quad = lane >> 4;
    int wv16 = wave * 16;

    // ================= Phase G: GEMM =================
    int ldr = tid >> 2, ldc8 = (tid & 3) * 8;    // A staging: row, k-offset
    int kp = tid >> 4, nq = tid & 15;            // B staging: k-pair, n-quad

    const float* apBase = hmat + (size_t)(m0 + ldr) * 1024 + ldc8;
    const float* bpBase = W_node + (size_t)(2 * kp) * 512 + n0 + nq * 4;

    f32x4 acc[4];
    #pragma unroll
    for (int i = 0; i < 4; ++i) acc[i] = (f32x4){0.f, 0.f, 0.f, 0.f};

    float4 a0 = *(const float4*)(apBase);
    float4 a1 = *(const float4*)(apBase + 4);
    float4 b0 = *(const float4*)(bpBase);
    float4 b1 = *(const float4*)(bpBase + 512);
    {
        s16x8 av;
        av[0] = (short)f2bf(a0.x); av[1] = (short)f2bf(a0.y);
        av[2] = (short)f2bf(a0.z); av[3] = (short)f2bf(a0.w);
        av[4] = (short)f2bf(a1.x); av[5] = (short)f2bf(a1.y);
        av[6] = (short)f2bf(a1.z); av[7] = (short)f2bf(a1.w);
        *(s16x8*)&As[ldr * 40 + ldc8] = av;
        const float* p0 = &b0.x; const float* p1 = &b1.x;
        #pragma unroll
        for (int u = 0; u < 4; ++u) {
            uint32_t pk = (uint32_t)f2bf(p0[u]) | ((uint32_t)f2bf(p1[u]) << 16);
            *(uint32_t*)&Bs[(nq * 4 + u) * 40 + 2 * kp] = pk;
        }
    }

    for (int it = 0; it < 32; ++it) {
        __syncthreads();
        if (it + 1 < 32) {
            const float* ap = apBase + (it + 1) * 32;
            a0 = *(const float4*)ap;
            a1 = *(const float4*)(ap + 4);
            const float* bp = bpBase + (size_t)(it + 1) * 32 * 512;
            b0 = *(const float4*)bp;
            b1 = *(const float4*)(bp + 512);
        }
        int cur = it & 1;
        s16x8 af = *(const s16x8*)&As[(cur * 64 + wv16 + l15) * 40 + quad * 8];
        #pragma unroll
        for (int nt = 0; nt < 4; ++nt) {
            s16x8 bf = *(const s16x8*)&Bs[(cur * 64 + nt * 16 + l15) * 40 + quad * 8];
            acc[nt] = __builtin_amdgcn_mfma_f32_16x16x32_bf16(af, bf, acc[nt], 0, 0, 0);
        }
        if (it + 1 < 32) {
            int nxt = cur ^ 1;
            s16x8 av;
            av[0] = (short)f2bf(a0.x); av[1] = (short)f2bf(a0.y);
            av[2] = (short)f2bf(a0.z); av[3] = (short)f2bf(a0.w);
            av[4] = (short)f2bf(a1.x); av[5] = (short)f2bf(a1.y);
            av[6] = (short)f2bf(a1.z); av[7] = (short)f2bf(a1.w);
            *(s16x8*)&As[(nxt * 64 + ldr) * 40 + ldc8] = av;
            const float* p0 = &b0.x; const float* p1 = &b1.x;
            #pragma unroll
            for (int u = 0; u < 4; ++u) {
                uint32_t pk = (uint32_t)f2bf(p0[u]) | ((uint32_t)f2bf(p1[u]) << 16);
                *(uint32_t*)&Bs[(nxt * 64 + nq * 4 + u) * 40 + 2 * kp] = pk;
            }
        }
    }
    __syncthreads();   // MFMAs done; As/Bs region free for overlay

    // ================= Phase E: epilogue =================
    // g-tile to LDS (fp32, bitwise round-4 accumulators)
    #pragma unroll
    for (int nt = 0; nt < 4; ++nt) {
        #pragma unroll
        for (int reg = 0; reg < 4; ++reg)
            gtile[wv16 + quad * 4 + reg][nt * 16 + l15] = acc[nt][reg];
    }
    // fused s_i/s_j row dots (identical fp order to round 4)
    {
        float wi[4], wj[4];
        #pragma unroll
        for (int nt = 0; nt < 4; ++nt) {
            wi[nt] = w_attn[nt * 16 + l15];
            wj[nt] = w_attn[64 + nt * 16 + l15];
        }
        float pi[4], pj[4];
        #pragma unroll
        for (int reg = 0; reg < 4; ++reg) { pi[reg] = 0.f; pj[reg] = 0.f; }
        #pragma unroll
        for (int nt = 0; nt < 4; ++nt) {
            #pragma unroll
            for (int reg = 0; reg < 4; ++reg) {
                pi[reg] += acc[nt][reg] * wi[nt];
                pj[reg] += acc[nt][reg] * wj[nt];
            }
        }
        #pragma unroll
        for (int mask = 1; mask < 16; mask <<= 1) {
            #pragma unroll
            for (int reg = 0; reg < 4; ++reg) {
                pi[reg] += __shfl_xor(pi[reg], mask);
                pj[reg] += __shfl_xor(pj[reg], mask);
            }
        }
        if (l15 == 0) {
            #pragma unroll
            for (int reg = 0; reg < 4; ++reg) {
                int r = wv16 + quad * 4 + reg;
                siS[r] = pi[reg];
                sjS[r] = pj[reg];
            }
        }
    }
    // adj ballots: wave w handles rows w*16..w*16+15
    for (int r16 = 0; r16 < 16; ++r16) {
        int i = wv16 + r16;
        float av = adj[(size_t)b * 4096 + (size_t)i * 64 + lane];
        unsigned long long mm = __ballot(av > 0.5f);
        int before = __popcll(mm & ((1ull << lane) - 1ull));
        if ((av > 0.5f) && before < 16) nbrS[i * 16 + before] = lane;
        if (lane == 0) cntS[i] = __popcll(mm);
    }
    // wv[:,h]
    if (tid < 128) {
        const float* row = W_edge + (size_t)tid * 512 + h * 64;
        const float* we = w_attn + 128;
        float s = 0.f;
        #pragma unroll 8
        for (int f = 0; f < 64; ++f) s += row[f] * we[f];
        wvS[tid] = s;
    }
    __syncthreads();

    // ================= Phase S: row_start scan + s_e slice =================
    if (wave == 0) {
        int c = cntS[lane];
        int inc = c;
        #pragma unroll
        for (int d = 1; d < 64; d <<= 1) {
            int u = __shfl_up(inc, d, 64);
            if (lane >= d) inc += u;
        }
        rsS[lane] = inc - c;
    }
    {
        // 16 lanes per edge, 4 edges/wave/pass, 64 passes (wave covers 256 edges)
        int c0 = l15 * 8;
        float4 wv0 = *(const float4*)&wvS[c0];
        float4 wv1 = *(const float4*)&wvS[c0 + 4];
        int esub = lane >> 4;
        #pragma unroll 2
        for (int p = 0; p < 64; ++p) {
            int e = wave * 256 + p * 4 + esub;
            const float4* er = (const float4*)(edge_attr + ((size_t)b * 1024 + e) * 128 + c0);
            float4 v0 = er[0], v1 = er[1];
            float s = v0.x * wv0.x + v0.y * wv0.y + v0.z * wv0.z + v0.w * wv0.w
                    + v1.x * wv1.x + v1.y * wv1.y + v1.z * wv1.z + v1.w * wv1.w;
            s += __shfl_xor(s, 1); s += __shfl_xor(s, 2);
            s += __shfl_xor(s, 4); s += __shfl_xor(s, 8);
            if (l15 == 0) s_eS[e] = s;
        }
    }
    __syncthreads();

    // ================= Phase X: scores + softmax =================
    {
        int grp = lane >> 4;
        int k = l15;
        #pragma unroll
        for (int p = 0; p < 4; ++p) {
            int i = wv16 + p * 4 + grp;
            int m_nb = cntS[i]; m_nb = (m_nb > 16) ? 16 : m_nb;
            float sc = -1e30f;
            if (k < m_nb) {
                int j = nbrS[i * 16 + k];
                float v = siS[i] + sjS[j] + s_eS[rsS[i] + k];
                sc = (v >= 0.f) ? v : SLOPE * v;
            }
            float mx = sc;
            #pragma unroll
            for (int mask = 1; mask < 16; mask <<= 1)
                mx = fmaxf(mx, __shfl_xor(mx, mask));
            float e = (k < m_nb) ? __expf(sc - mx) : 0.f;
            float t = e;
            #pragma unroll
            for (int mask = 1; mask < 16; mask <<= 1)
                t += __shfl_xor(t, mask);
            a_sS[i * 16 + k] = e / t;
        }
    }
    __syncthreads();

    // ================= Phase A: aggregate =================
    {
        int i = tid >> 2;
        int f0 = (tid & 3) * 16;
        int m_nb = cntS[i]; m_nb = (m_nb > 16) ? 16 : m_nb;
        f32x4 o0 = {0.f,0.f,0.f,0.f}, o1 = o0, o2 = o0, o3 = o0;
        for (int kk = 0; kk < m_nb; ++kk) {
            float ak = a_sS[i * 16 + kk];
            int j = nbrS[i * 16 + kk];
            const float* gr = &gtile[j][f0];
            o0 += ak * *(const f32x4*)(gr);
            o1 += ak * *(const f32x4*)(gr + 4);
            o2 += ak * *(const f32x4*)(gr + 8);
            o3 += ak * *(const f32x4*)(gr + 12);
        }
        float* op = out + (size_t)(b * 64 + i) * 512 + h * 64 + f0;
        *(f32x4*)(op)      = o0;
        *(f32x4*)(op + 4)  = o1;
        *(f32x4*)(op + 8)  = o2;
        *(f32x4*)(op + 12) = o3;
    }
}

// ---------------------------------------------------------------------------
extern "C" void kernel_launch(void* const* d_in, const int* in_sizes, int n_in,
                              void* d_out, int out_size, void* d_ws, size_t ws_size,
                              hipStream_t stream) {
    const float* h_in      = (const float*)d_in[0];   // (16,64,1024)
    const float* adj_mat   = (const float*)d_in[1];   // (16,64,64)
    const float* edge_attr = (const float*)d_in[2];   // (16,1024,128)
    const float* W_node    = (const float*)d_in[3];   // (1024,512)
    const float* W_edge    = (const float*)d_in[4];   // (128,512)
    const float* w_attn    = (const float*)d_in[5];   // (192,)
    float* out = (float*)d_out;                       // (16,64,512) fp32

    (void)d_ws; (void)ws_size;
    gat_fused<<<128, 256, 0, stream>>>(h_in, adj_mat, edge_attr,
                                       W_node, W_edge, w_attn, out);
}

// Round 8
// 97.450 us; speedup vs baseline: 2.8642x; 1.2932x over previous
//
#include <hip/hip_runtime.h>
#include <hip/hip_bf16.h>
#include <stdint.h>

#define SLOPE 0.2f

typedef short s16x8 __attribute__((ext_vector_type(8)));
typedef float f32x4 __attribute__((ext_vector_type(4)));

__device__ __forceinline__ unsigned short f2bf(float x) {
    union { float f; uint32_t u; } v; v.f = x;
    uint32_t u = v.u;
    return (unsigned short)((u + 0x7FFFu + ((u >> 16) & 1u)) >> 16);  // RNE
}

// ---------------------------------------------------------------------------
// main: blocks 0..127 : GEMM 64x64 tile (mt=bx>>3, head=bx&7). Round-6 Phase-G
//                       body verbatim (in-block B transpose from W_node, dbuf
//                       K-loop, s16x8 staging) + round-4 epilogue verbatim
//                       (fp32 g write + fused s_i/s_j, bitwise round-4 order).
//       blocks 128..191: s_e[e][h] = edge_attr[e,:] . wv[:,h]  (wv local)
//       blocks 192..207: row_start scans
// All three roles individually passed replay validation in rounds 4/6.
// ---------------------------------------------------------------------------
__global__ __launch_bounds__(256)
void main_kernel(const float* __restrict__ hmat,       // [1024][1024]
                 const float* __restrict__ adj,        // [16][64][64]
                 const float* __restrict__ edge_attr,  // [16384][128]
                 const float* __restrict__ W_node,     // [1024][512]
                 const float* __restrict__ W_edge,     // [128][512]
                 const float* __restrict__ w_attn,     // [192]
                 float* __restrict__ g,                // [1024][512]
                 float* __restrict__ s_e,              // [16384][8]
                 float* __restrict__ s_i,              // [1024][8]
                 float* __restrict__ s_j,              // [1024][8]
                 int* __restrict__ row_start)          // [1024]
{
    __shared__ __align__(16) char U[20480];
    unsigned short* As = (unsigned short*)U;             // [2][64][40] = 10240 B
    unsigned short* Bs = (unsigned short*)(U + 10240);   // [2][64][40] = 10240 B
    float* wvs = (float*)U;                              // edge role overlay

    int bx = blockIdx.x, tid = threadIdx.x;

    if (bx < 128) {
        // ================= GEMM role (round-6 Phase G, verbatim) =============
        int head = bx & 7, mt = bx >> 3;
        int n0 = head * 64, m0 = mt * 64;
        int wave = tid >> 6, lane = tid & 63;
        int l15 = lane & 15, quad = lane >> 4;
        int wv16 = wave * 16;

        int ldr = tid >> 2, ldc8 = (tid & 3) * 8;    // A staging
        int kp = tid >> 4, nq = tid & 15;            // B staging (transpose)

        const float* apBase = hmat + (size_t)(m0 + ldr) * 1024 + ldc8;
        const float* bpBase = W_node + (size_t)(2 * kp) * 512 + n0 + nq * 4;

        f32x4 acc[4];
        #pragma unroll
        for (int i = 0; i < 4; ++i) acc[i] = (f32x4){0.f, 0.f, 0.f, 0.f};

        float4 a0 = *(const float4*)(apBase);
        float4 a1 = *(const float4*)(apBase + 4);
        float4 b0 = *(const float4*)(bpBase);
        float4 b1 = *(const float4*)(bpBase + 512);
        {
            s16x8 av;
            av[0] = (short)f2bf(a0.x); av[1] = (short)f2bf(a0.y);
            av[2] = (short)f2bf(a0.z); av[3] = (short)f2bf(a0.w);
            av[4] = (short)f2bf(a1.x); av[5] = (short)f2bf(a1.y);
            av[6] = (short)f2bf(a1.z); av[7] = (short)f2bf(a1.w);
            *(s16x8*)&As[ldr * 40 + ldc8] = av;
            const float* p0 = &b0.x; const float* p1 = &b1.x;
            #pragma unroll
            for (int u = 0; u < 4; ++u) {
                uint32_t pk = (uint32_t)f2bf(p0[u]) | ((uint32_t)f2bf(p1[u]) << 16);
                *(uint32_t*)&Bs[(nq * 4 + u) * 40 + 2 * kp] = pk;
            }
        }

        for (int it = 0; it < 32; ++it) {
            __syncthreads();
            if (it + 1 < 32) {
                const float* ap = apBase + (it + 1) * 32;
                a0 = *(const float4*)ap;
                a1 = *(const float4*)(ap + 4);
                const float* bp = bpBase + (size_t)(it + 1) * 32 * 512;
                b0 = *(const float4*)bp;
                b1 = *(const float4*)(bp + 512);
            }
            int cur = it & 1;
            s16x8 af = *(const s16x8*)&As[(cur * 64 + wv16 + l15) * 40 + quad * 8];
            #pragma unroll
            for (int nt = 0; nt < 4; ++nt) {
                s16x8 bf = *(const s16x8*)&Bs[(cur * 64 + nt * 16 + l15) * 40 + quad * 8];
                acc[nt] = __builtin_amdgcn_mfma_f32_16x16x32_bf16(af, bf, acc[nt], 0, 0, 0);
            }
            if (it + 1 < 32) {
                int nxt = cur ^ 1;
                s16x8 av;
                av[0] = (short)f2bf(a0.x); av[1] = (short)f2bf(a0.y);
                av[2] = (short)f2bf(a0.z); av[3] = (short)f2bf(a0.w);
                av[4] = (short)f2bf(a1.x); av[5] = (short)f2bf(a1.y);
                av[6] = (short)f2bf(a1.z); av[7] = (short)f2bf(a1.w);
                *(s16x8*)&As[(nxt * 64 + ldr) * 40 + ldc8] = av;
                const float* p0 = &b0.x; const float* p1 = &b1.x;
                #pragma unroll
                for (int u = 0; u < 4; ++u) {
                    uint32_t pk = (uint32_t)f2bf(p0[u]) | ((uint32_t)f2bf(p1[u]) << 16);
                    *(uint32_t*)&Bs[(nxt * 64 + nq * 4 + u) * 40 + 2 * kp] = pk;
                }
            }
        }

        // ============ epilogue (round-4 verbatim: g + fused s_i/s_j) =========
        float wi[4], wj[4];
        #pragma unroll
        for (int nt = 0; nt < 4; ++nt) {
            wi[nt] = w_attn[nt * 16 + l15];
            wj[nt] = w_attn[64 + nt * 16 + l15];
        }
        float pi[4], pj[4];
        #pragma unroll
        for (int reg = 0; reg < 4; ++reg) { pi[reg] = 0.f; pj[reg] = 0.f; }
        #pragma unroll
        for (int nt = 0; nt < 4; ++nt) {
            #pragma unroll
            for (int reg = 0; reg < 4; ++reg) {
                int gm = m0 + wv16 + quad * 4 + reg;
                int gn = n0 + nt * 16 + l15;
                g[(size_t)gm * 512 + gn] = acc[nt][reg];
                pi[reg] += acc[nt][reg] * wi[nt];
                pj[reg] += acc[nt][reg] * wj[nt];
            }
        }
        #pragma unroll
        for (int mask = 1; mask < 16; mask <<= 1) {
            #pragma unroll
            for (int reg = 0; reg < 4; ++reg) {
                pi[reg] += __shfl_xor(pi[reg], mask);
                pj[reg] += __shfl_xor(pj[reg], mask);
            }
        }
        if (l15 == 0) {
            #pragma unroll
            for (int reg = 0; reg < 4; ++reg) {
                int r = m0 + wv16 + quad * 4 + reg;
                s_i[(size_t)r * 8 + head] = pi[reg];
                s_j[(size_t)r * 8 + head] = pj[reg];
            }
        }
    } else if (bx < 192) {
        // ================= edge-score role (wv local; rounds 6/7) ============
        {
            int c = tid & 127, half = tid >> 7;
            const float* we = w_attn + 128;
            #pragma unroll
            for (int hh = 0; hh < 4; ++hh) {
                int h = half * 4 + hh;
                float s = 0.f;
                const float* row = W_edge + (size_t)c * 512 + h * 64;
                #pragma unroll 8
                for (int f = 0; f < 64; ++f) s += row[f] * we[f];
                wvs[c * 8 + h] = s;
            }
        }
        __syncthreads();
        int e = (bx - 128) * 256 + tid;
        const float4* erow = (const float4*)(edge_attr + (size_t)e * 128);
        f32x4 accl = {0.f, 0.f, 0.f, 0.f};
        f32x4 acch = {0.f, 0.f, 0.f, 0.f};
        for (int c4 = 0; c4 < 32; ++c4) {
            float4 v = erow[c4];
            #pragma unroll
            for (int u = 0; u < 4; ++u) {
                int c = c4 * 4 + u;
                f32x4 w0 = *(const f32x4*)&wvs[c * 8];
                f32x4 w1 = *(const f32x4*)&wvs[c * 8 + 4];
                float x = (u == 0) ? v.x : (u == 1) ? v.y : (u == 2) ? v.z : v.w;
                accl += x * w0;
                acch += x * w1;
            }
        }
        *(f32x4*)(s_e + (size_t)e * 8)     = accl;
        *(f32x4*)(s_e + (size_t)e * 8 + 4) = acch;
    } else {
        // ================= row_start role =================
        int b = bx - 192;
        if (tid < 64) {
            const float* row = adj + (size_t)b * 4096 + (size_t)tid * 64;
            int cnt = 0;
            #pragma unroll 8
            for (int j = 0; j < 64; ++j) cnt += (row[j] > 0.5f) ? 1 : 0;
            int inc = cnt;
            #pragma unroll
            for (int d = 1; d < 64; d <<= 1) {
                int u = __shfl_up(inc, d, 64);
                if (tid >= d) inc += u;
            }
            row_start[b * 64 + tid] = inc - cnt;
        }
    }
}

// ---------------------------------------------------------------------------
// attn: one block per (b,i). Round-4 version verbatim (replay-proven).
// ---------------------------------------------------------------------------
__global__ __launch_bounds__(256)
void attn_kernel(const float* __restrict__ g,          // [1024][512] fp32
                 const float* __restrict__ adj,        // [16][64][64]
                 const float* __restrict__ s_e,        // [16384][8]
                 const float* __restrict__ s_i,        // [1024][8]
                 const float* __restrict__ s_j,        // [1024][8]
                 const int*   __restrict__ row_start,  // [1024]
                 float* __restrict__ out)              // [1024][512]
{
    __shared__ __align__(16) float gs[16][516];
    __shared__ float se_s[16][8];
    __shared__ float sj_s[16][8];
    __shared__ float a_s[16][8];
    __shared__ float si_s[8];
    __shared__ int nbr[16];
    __shared__ int m_nb_s;

    int bi = blockIdx.x;
    int b = bi >> 6, i = bi & 63;
    int tid = threadIdx.x;

    if (tid < 64) {
        float av = adj[(size_t)b * 4096 + (size_t)i * 64 + tid];
        unsigned long long m = __ballot(av > 0.5f);
        if (av > 0.5f) {
            int before = __popcll(m & ((1ull << tid) - 1ull));
            if (before < 16) nbr[before] = tid;
        }
        if (tid == 0) {
            int c = __popcll(m);
            m_nb_s = (c > 16) ? 16 : c;
        }
    }
    __syncthreads();

    int m_nb = m_nb_s;
    int rs = row_start[bi];

    int slot = tid >> 4, l16 = tid & 15;
    if (slot < m_nb) {
        const float4* src4 = (const float4*)(g + (size_t)(b * 64 + nbr[slot]) * 512);
        #pragma unroll
        for (int j = 0; j < 8; ++j) {
            int q = j * 16 + l16;
            *(float4*)&gs[slot][q * 4] = src4[q];
        }
    }
    if (tid < 128) {
        int k = tid >> 3, h = tid & 7;
        if (k < m_nb) {
            se_s[k][h] = s_e[(size_t)(b * 1024 + rs + k) * 8 + h];
            sj_s[k][h] = s_j[(size_t)(b * 64 + nbr[k]) * 8 + h];
        }
    } else if (tid < 136) {
        si_s[tid - 128] = s_i[(size_t)bi * 8 + (tid - 128)];
    }
    __syncthreads();

    if (tid < 8) {
        int h = tid;
        float si = si_s[h];
        float sc[16];
        float mx = -1e30f;
        for (int k = 0; k < m_nb; ++k) {
            float v = si + sj_s[k][h] + se_s[k][h];
            v = (v >= 0.f) ? v : SLOPE * v;
            sc[k] = v;
            mx = fmaxf(mx, v);
        }
        float ssum = 0.f;
        for (int k = 0; k < m_nb; ++k) {
            float e = __expf(sc[k] - mx);
            a_s[k][h] = e;
            ssum += e;
        }
        float inv = 1.f / ssum;
        for (int k = 0; k < m_nb; ++k) a_s[k][h] *= inv;
    }
    __syncthreads();

    int c0 = tid * 2;
    int h = tid >> 5;
    float a0 = 0.f, a1 = 0.f;
    for (int k = 0; k < m_nb; ++k) {
        float ak = a_s[k][h];
        a0 += ak * gs[k][c0];
        a1 += ak * gs[k][c0 + 1];
    }
    out[(size_t)bi * 512 + c0]     = a0;
    out[(size_t)bi * 512 + c0 + 1] = a1;
}

// ---------------------------------------------------------------------------
extern "C" void kernel_launch(void* const* d_in, const int* in_sizes, int n_in,
                              void* d_out, int out_size, void* d_ws, size_t ws_size,
                              hipStream_t stream) {
    const float* h_in      = (const float*)d_in[0];   // (16,64,1024)
    const float* adj_mat   = (const float*)d_in[1];   // (16,64,64)
    const float* edge_attr = (const float*)d_in[2];   // (16,1024,128)
    const float* W_node    = (const float*)d_in[3];   // (1024,512)
    const float* W_edge    = (const float*)d_in[4];   // (128,512)
    const float* w_attn    = (const float*)d_in[5];   // (192,)
    float* out = (float*)d_out;                       // (16,64,512) fp32

    char* ws = (char*)d_ws;
    float* g         = (float*)(ws + 0x000000);       // 2 MB
    float* s_e       = (float*)(ws + 0x200000);       // 512 KB
    float* s_i       = (float*)(ws + 0x280000);       // 32 KB
    float* s_j       = (float*)(ws + 0x288000);       // 32 KB
    int*   row_start = (int*)  (ws + 0x290000);       // 4 KB

    main_kernel<<<208, 256, 0, stream>>>(h_in, adj_mat, edge_attr,
                                         W_node, W_edge, w_attn,
                                         g, s_e, s_i, s_j, row_start);
    attn_kernel<<<1024, 256, 0, stream>>>(g, adj_mat, s_e, s_i, s_j,
                                          row_start, out);
}